// Round 8
// baseline (625.623 us; speedup 1.0000x reference)
//
#include <hip/hip_runtime.h>
#include <hip/hip_bf16.h>

// Problem constants
#define BD   256
#define SD   512
#define HD   768
#define IMGD 2048
#define TWOH 1536
constexpr float EPSV  = 1e-5f;
constexpr float SCALE = 0.036084391824351615f;  // 1/sqrt(768)
constexpr int   SPLIT = 4;
constexpr int   SBLK  = SD / SPLIT;             // 128 rows per slice

typedef __attribute__((ext_vector_type(8))) short short8;
typedef __attribute__((ext_vector_type(4))) float f32x4;

__device__ __forceinline__ short f2bs(float x) {
    __hip_bfloat16 h = __float2bfloat16(x);
    return __builtin_bit_cast(short, h);
}
__device__ __forceinline__ float4 f4sum(float4 a, float4 b) {
    return make_float4(a.x + b.x, a.y + b.y, a.z + b.z, a.w + b.w);
}
__device__ __forceinline__ float4 f4fma(float s, float4 v, float4 acc) {
    return make_float4(fmaf(s, v.x, acc.x), fmaf(s, v.y, acc.y),
                       fmaf(s, v.z, acc.z), fmaf(s, v.w, acc.w));
}
__device__ __forceinline__ float red16(float v) {   // sum within 16-lane group
    v += __shfl_xor(v, 1); v += __shfl_xor(v, 2);
    v += __shfl_xor(v, 4); v += __shfl_xor(v, 8);
    return v;
}
__device__ __forceinline__ short8 ld_b64x2(const __hip_bfloat16* p) {
    union { unsigned long long u[2]; short8 s; } cv;
    cv.u[0] = *(const unsigned long long*)p;
    cv.u[1] = *(const unsigned long long*)(p + 4);
    return cv.s;
}

struct GemmSmem {
    __hip_bfloat16 As[2][64][40];
    __hip_bfloat16 Bs[2][64][40];
};

// ---------------------------------------------------------------------------
// 64x64-tile GEMM core (unchanged, verified) — used by stage1/stage2/fallback.
// ---------------------------------------------------------------------------
template<bool TRANSB, class AF, class BF>
__device__ __forceinline__ void gemm_core(GemmSmem& smem, AF aload, BF bload,
        const float* __restrict__ bias, float* __restrict__ C,
        int N, int m0, int n0, int NT) {
    const int tid  = threadIdx.x;
    const int w    = tid >> 6, lane = tid & 63;
    const int wr   = w >> 1,  wc   = w & 1;
    const int rsel = lane & 15, ks = (lane >> 4) * 8;
    const int arow = tid >> 2, akc = (tid & 3) * 8;
    const int bkk  = tid >> 3, bnc = (tid & 7) * 8;

    float4 a0v[2], a1v[2], b0v[2], b1v[2];

    auto issue = [&](int slot, int t) {
        aload(t, a0v[slot], a1v[slot]);
        bload(t, b0v[slot], b1v[slot]);
    };
    auto commit = [&](int buf, int slot) {
        short8 pk;
        pk[0]=f2bs(a0v[slot].x); pk[1]=f2bs(a0v[slot].y);
        pk[2]=f2bs(a0v[slot].z); pk[3]=f2bs(a0v[slot].w);
        pk[4]=f2bs(a1v[slot].x); pk[5]=f2bs(a1v[slot].y);
        pk[6]=f2bs(a1v[slot].z); pk[7]=f2bs(a1v[slot].w);
        *(short8*)&smem.As[buf][arow][akc] = pk;
        if (TRANSB) {
            short8 qk;
            qk[0]=f2bs(b0v[slot].x); qk[1]=f2bs(b0v[slot].y);
            qk[2]=f2bs(b0v[slot].z); qk[3]=f2bs(b0v[slot].w);
            qk[4]=f2bs(b1v[slot].x); qk[5]=f2bs(b1v[slot].y);
            qk[6]=f2bs(b1v[slot].z); qk[7]=f2bs(b1v[slot].w);
            *(short8*)&smem.Bs[buf][arow][akc] = qk;
        } else {
            smem.Bs[buf][bnc + 0][bkk] = __float2bfloat16(b0v[slot].x);
            smem.Bs[buf][bnc + 1][bkk] = __float2bfloat16(b0v[slot].y);
            smem.Bs[buf][bnc + 2][bkk] = __float2bfloat16(b0v[slot].z);
            smem.Bs[buf][bnc + 3][bkk] = __float2bfloat16(b0v[slot].w);
            smem.Bs[buf][bnc + 4][bkk] = __float2bfloat16(b1v[slot].x);
            smem.Bs[buf][bnc + 5][bkk] = __float2bfloat16(b1v[slot].y);
            smem.Bs[buf][bnc + 6][bkk] = __float2bfloat16(b1v[slot].z);
            smem.Bs[buf][bnc + 7][bkk] = __float2bfloat16(b1v[slot].w);
        }
    };

    f32x4 zero = {0.f, 0.f, 0.f, 0.f};
    f32x4 acc[2][2] = {{zero, zero}, {zero, zero}};

    issue(0, 0);
    commit(0, 0);
    if (NT > 1) issue(1, 1);
    __syncthreads();

    for (int t = 0; t < NT; ++t) {
        const int cur = t & 1;
        short8 A0 = *(const short8*)&smem.As[cur][wr * 32 + rsel][ks];
        short8 A1 = *(const short8*)&smem.As[cur][wr * 32 + 16 + rsel][ks];
        short8 B0 = *(const short8*)&smem.Bs[cur][wc * 32 + rsel][ks];
        short8 B1 = *(const short8*)&smem.Bs[cur][wc * 32 + 16 + rsel][ks];
        if (t + 1 < NT) commit(cur ^ 1, (t + 1) & 1);
        if (t + 2 < NT) issue(cur, t + 2);
        acc[0][0] = __builtin_amdgcn_mfma_f32_16x16x32_bf16(A0, B0, acc[0][0], 0, 0, 0);
        acc[0][1] = __builtin_amdgcn_mfma_f32_16x16x32_bf16(A0, B1, acc[0][1], 0, 0, 0);
        acc[1][0] = __builtin_amdgcn_mfma_f32_16x16x32_bf16(A1, B0, acc[1][0], 0, 0, 0);
        acc[1][1] = __builtin_amdgcn_mfma_f32_16x16x32_bf16(A1, B1, acc[1][1], 0, 0, 0);
        __syncthreads();
    }

    const int colb = lane & 15, rowb = (lane >> 4) * 4;
    #pragma unroll
    for (int fm = 0; fm < 2; ++fm)
        #pragma unroll
        for (int fn = 0; fn < 2; ++fn)
            #pragma unroll
            for (int r = 0; r < 4; ++r) {
                int row = m0 + wr * 32 + fm * 16 + rowb + r;
                int col = n0 + wc * 32 + fn * 16 + colb;
                float v = acc[fm][fn][r];
                if (bias) v += bias[col];
                C[(size_t)row * N + col] = v;
            }
}

// ---------------------------------------------------------------------------
// Stage 1 (unchanged from round 7)
// ---------------------------------------------------------------------------
__global__ __launch_bounds__(256) void stage1(const float* __restrict__ imgf,
                                              const float* __restrict__ Wp,
                                              const float* __restrict__ bp,
                                              const float* __restrict__ Wiq,
                                              const float* __restrict__ Wtk,
                                              const float* __restrict__ biq,
                                              float* __restrict__ Pp,
                                              float* __restrict__ Wqkp,
                                              float* __restrict__ v1) {
    __shared__ GemmSmem smem;
    const int blk = blockIdx.x, tid = threadIdx.x;
    const int arow = tid >> 2, akc = (tid & 3) * 8;
    const int bkk  = tid >> 3, bnc = (tid & 7) * 8;
    if (blk < 192) {
        const int part = blk / 48, tile = blk % 48;
        const int m0 = (tile / 12) * 64, n0 = (tile % 12) * 64, kbeg = part * 512;
        const float* ap = &imgf[(size_t)(m0 + arow) * IMGD + kbeg + akc];
        const float* bq = &Wp[(size_t)(kbeg + bkk) * HD + n0 + bnc];
        auto al = [&](int t, float4& v0, float4& v1_) {
            const float* p = ap + t * 32;
            v0 = *(const float4*)p; v1_ = *(const float4*)(p + 4);
        };
        auto bl = [&](int t, float4& v0, float4& v1_) {
            const float* p = bq + (size_t)t * 32 * HD;
            v0 = *(const float4*)p; v1_ = *(const float4*)(p + 4);
        };
        gemm_core<false>(smem, al, bl, part == 0 ? bp : nullptr,
                         Pp + (size_t)part * BD * HD, HD, m0, n0, 16);
    } else if (blk < 768) {
        const int b2 = blk - 192, part = b2 / 144, tile = b2 % 144;
        const int m0 = (tile / 12) * 64, n0 = (tile % 12) * 64, kbeg = part * 192;
        const float* ap = &Wiq[(size_t)(m0 + arow) * HD + kbeg + akc];
        const float* bq = &Wtk[(size_t)(n0 + arow) * HD + kbeg + akc];
        auto al = [&](int t, float4& v0, float4& v1_) {
            const float* p = ap + t * 32;
            v0 = *(const float4*)p; v1_ = *(const float4*)(p + 4);
        };
        auto bl = [&](int t, float4& v0, float4& v1_) {
            const float* p = bq + t * 32;
            v0 = *(const float4*)p; v1_ = *(const float4*)(p + 4);
        };
        gemm_core<true>(smem, al, bl, nullptr,
                        Wqkp + (size_t)part * HD * HD, HD, m0, n0, 6);
    } else {
        const int b2 = blk - 768;
        const int w = tid >> 6, lane = tid & 63;
        float bq[12];
        #pragma unroll
        for (int c = 0; c < 12; ++c) bq[c] = biq[c * 64 + lane];
        const int d0 = b2 * 64 + w * 16;
        for (int i = 0; i < 16; ++i) {
            const float* row = &Wtk[(size_t)(d0 + i) * HD];
            float p = 0.f;
            #pragma unroll
            for (int c = 0; c < 12; ++c) p = fmaf(row[c * 64 + lane], bq[c], p);
            #pragma unroll
            for (int off = 32; off > 0; off >>= 1) p += __shfl_xor(p, off);
            if (lane == 0) v1[d0 + i] = p;
        }
    }
}

// Stage 2 (unchanged from round 7)
__global__ __launch_bounds__(256) void stage2(const float* __restrict__ Pp,
                                              const float* __restrict__ Wqkp,
                                              const float* __restrict__ v1,
                                              const float* __restrict__ Wiv,
                                              const float* __restrict__ biv,
                                              float* __restrict__ qtp,
                                              float* __restrict__ ivp) {
    __shared__ GemmSmem smem;
    const int blk = blockIdx.x, tid = threadIdx.x;
    const int arow = tid >> 2, akc = (tid & 3) * 8;
    const int bkk  = tid >> 3, bnc = (tid & 7) * 8;
    const bool isqt = blk < 192;
    const int b2 = isqt ? blk : blk - 192;
    const int part = b2 / 48, tile = b2 % 48;
    const int m0 = (tile / 12) * 64, n0 = (tile % 12) * 64, kbeg = part * 192;

    const float* ap = &Pp[(size_t)(m0 + arow) * HD + kbeg + akc];
    auto al = [&](int t, float4& v0, float4& v1_) {
        const float* p = ap + t * 32;
        float4 x0 = *(const float4*)p, x1 = *(const float4*)(p + 4);
        #pragma unroll
        for (int q = 1; q < 4; ++q) {
            const float* r = p + (size_t)q * BD * HD;
            x0 = f4sum(x0, *(const float4*)r);
            x1 = f4sum(x1, *(const float4*)(r + 4));
        }
        v0 = x0; v1_ = x1;
    };
    if (isqt) {
        const float* bq = &Wqkp[(size_t)(kbeg + bkk) * HD + n0 + bnc];
        auto bl = [&](int t, float4& v0, float4& v1_) {
            const float* p = bq + (size_t)t * 32 * HD;
            float4 x0 = *(const float4*)p, x1 = *(const float4*)(p + 4);
            #pragma unroll
            for (int q = 1; q < 4; ++q) {
                const float* r = p + (size_t)q * HD * HD;
                x0 = f4sum(x0, *(const float4*)r);
                x1 = f4sum(x1, *(const float4*)(r + 4));
            }
            v0 = x0; v1_ = x1;
        };
        gemm_core<false>(smem, al, bl, part == 0 ? v1 : nullptr,
                         qtp + (size_t)part * BD * HD, HD, m0, n0, 6);
    } else {
        const float* bq = &Wiv[(size_t)(kbeg + bkk) * HD + n0 + bnc];
        auto bl = [&](int t, float4& v0, float4& v1_) {
            const float* p = bq + (size_t)t * 32 * HD;
            v0 = *(const float4*)p; v1_ = *(const float4*)(p + 4);
        };
        gemm_core<false>(smem, al, bl, part == 0 ? biv : nullptr,
                         ivp + (size_t)part * BD * HD, HD, m0, n0, 6);
    }
}

// ---------------------------------------------------------------------------
// Streaming flash pass (unchanged from round 7)
// ---------------------------------------------------------------------------
__global__ __launch_bounds__(256) void stream_attn(const float* __restrict__ tf,
                                                   const float* __restrict__ qtp,
                                                   float* __restrict__ pacc,
                                                   float* __restrict__ ml) {
    const int tid = threadIdx.x, w = tid >> 6, lane = tid & 63;
    const int item = blockIdx.x;
    const int b = item >> 2, sl = item & 3;
    __shared__ float sacc[4][HD];
    __shared__ float sm_[4], sl_[4];

    float q[12];
    {
        const float* qp = &qtp[b * HD];
        #pragma unroll
        for (int c = 0; c < 3; ++c) {
            float4 v = *(const float4*)&qp[c * 256 + 4 * lane];
            #pragma unroll
            for (int p = 1; p < 4; ++p)
                v = f4sum(v, *(const float4*)&qp[(size_t)p * BD * HD + c * 256 + 4 * lane]);
            q[c*4+0] = v.x; q[c*4+1] = v.y; q[c*4+2] = v.z; q[c*4+3] = v.w;
        }
    }
    float a[12];
    #pragma unroll
    for (int j = 0; j < 12; ++j) a[j] = 0.f;
    float m = -INFINITY, l = 0.f;

    const int r0 = sl * SBLK + w * (SBLK / 4);
    const float* base = &tf[((size_t)b * SD + r0) * HD];

    float tA[12], tB[12];
    auto loadrow = [&](int i, float* t) {
        const float* row = base + (size_t)i * HD;
        #pragma unroll
        for (int c = 0; c < 3; ++c) {
            float4 v = *(const float4*)&row[c * 256 + 4 * lane];
            t[c*4+0] = v.x; t[c*4+1] = v.y; t[c*4+2] = v.z; t[c*4+3] = v.w;
        }
    };
    auto process = [&](const float* t) {
        float p = 0.f;
        #pragma unroll
        for (int j = 0; j < 12; ++j) p = fmaf(t[j], q[j], p);
        #pragma unroll
        for (int off = 32; off > 0; off >>= 1) p += __shfl_xor(p, off);
        float score = p * SCALE;
        float mn = fmaxf(m, score);
        float eo = __expf(m - mn);
        float en = __expf(score - mn);
        l = fmaf(l, eo, en);
        #pragma unroll
        for (int j = 0; j < 12; ++j) a[j] = fmaf(a[j], eo, en * t[j]);
        m = mn;
    };

    loadrow(0, tA);
    for (int i = 0; i < 32; i += 2) {
        loadrow(i + 1, tB);
        process(tA);
        if (i + 2 < 32) loadrow(i + 2, tA);
        process(tB);
    }

    #pragma unroll
    for (int c = 0; c < 3; ++c)
        #pragma unroll
        for (int j = 0; j < 4; ++j)
            sacc[w][c * 256 + 4 * lane + j] = a[c * 4 + j];
    if (lane == 0) { sm_[w] = m; sl_[w] = l; }
    __syncthreads();
    float gm = fmaxf(fmaxf(sm_[0], sm_[1]), fmaxf(sm_[2], sm_[3]));
    float f0 = __expf(sm_[0] - gm), f1 = __expf(sm_[1] - gm);
    float f2 = __expf(sm_[2] - gm), f3 = __expf(sm_[3] - gm);
    float gl = f0 * sl_[0] + f1 * sl_[1] + f2 * sl_[2] + f3 * sl_[3];
    float* outp = &pacc[(size_t)item * HD];
    #pragma unroll
    for (int jj = 0; jj < 3; ++jj) {
        int c = jj * 256 + tid;
        outp[c] = f0 * sacc[0][c] + f1 * sacc[1][c] + f2 * sacc[2][c] + f3 * sacc[3][c];
    }
    if (tid == 0) { ml[item * 2] = gm; ml[item * 2 + 1] = gl; }
}

// ===========================================================================
// tail8: ctx-merge + (ctx@Wtv) + LN_i + LN_t + gate + (wtd@Wf) + LN_f + gelu,
// one kernel. 8 blocks x 512 thr; block owns 32 full rows. Dynamic LDS 154KB.
// Arena: Actx bf16[32][776] @0 (GEMM1 A); A2 bf16[32][1544] @0 (GEMM2 A,
// written after GEMM1); Bs bf16[768][36] @98816 (B staging, both GEMMs).
// ===========================================================================
#define TAIL_LDS_BYTES (98816 + 55296)
#define ACTX_S 776
#define A2_S   1544
#define BS_S   36

// Full-width GEMM sub-loop: acc[2][6] += A[32 x KDIM] @ Bsrc[KDIM x 768].
template<int KDIM, int ASTRIDE>
__device__ __forceinline__ void tail_gemm(const __hip_bfloat16* __restrict__ A,
        __hip_bfloat16* __restrict__ Bs, const float* __restrict__ Bsrc,
        f32x4 (&acc)[2][6], int tid, int w, int lane) {
    const int rsel = lane & 15, ks = (lane >> 4) * 8;
    const int n0w = w * 96;
    const int kk = tid >> 4, nc = (tid & 15) * 48;

    float4 pre[12];
    {
        const float* src = &Bsrc[(size_t)kk * HD + nc];
        #pragma unroll
        for (int i = 0; i < 12; ++i) pre[i] = *(const float4*)(src + i * 4);
    }
    for (int k0 = 0; k0 < KDIM; k0 += 32) {
        __syncthreads();                       // prev iter's B reads done
        #pragma unroll
        for (int i = 0; i < 12; ++i) {         // transpose-write 48 bf16
            int n = nc + i * 4;
            Bs[(n + 0) * BS_S + kk] = __float2bfloat16(pre[i].x);
            Bs[(n + 1) * BS_S + kk] = __float2bfloat16(pre[i].y);
            Bs[(n + 2) * BS_S + kk] = __float2bfloat16(pre[i].z);
            Bs[(n + 3) * BS_S + kk] = __float2bfloat16(pre[i].w);
        }
        if (k0 + 32 < KDIM) {                  // prefetch next slice
            const float* src = &Bsrc[(size_t)(k0 + 32 + kk) * HD + nc];
            #pragma unroll
            for (int i = 0; i < 12; ++i) pre[i] = *(const float4*)(src + i * 4);
        }
        __syncthreads();                       // B staged
        short8 af0 = *(const short8*)&A[(size_t)(rsel) * ASTRIDE + k0 + ks];
        short8 af1 = *(const short8*)&A[(size_t)(16 + rsel) * ASTRIDE + k0 + ks];
        #pragma unroll
        for (int fn = 0; fn < 6; ++fn) {
            short8 bf = ld_b64x2(&Bs[(size_t)(n0w + fn * 16 + rsel) * BS_S + ks]);
            acc[0][fn] = __builtin_amdgcn_mfma_f32_16x16x32_bf16(af0, bf, acc[0][fn], 0, 0, 0);
            acc[1][fn] = __builtin_amdgcn_mfma_f32_16x16x32_bf16(af1, bf, acc[1][fn], 0, 0, 0);
        }
    }
    __syncthreads();
}

__global__ __launch_bounds__(512) void tail8(
        const float* __restrict__ pacc, const float* __restrict__ ml,
        const float* __restrict__ Wtv, const float* __restrict__ btv,
        const float* __restrict__ Pp,  const float* __restrict__ ivp,
        const float* __restrict__ tf,
        const float* __restrict__ in_g, const float* __restrict__ in_b,
        const float* __restrict__ tn_g, const float* __restrict__ tn_b,
        const float* __restrict__ Wg,  const float* __restrict__ bg,
        const float* __restrict__ Wf,  const float* __restrict__ bff,
        const float* __restrict__ fn_g, const float* __restrict__ fn_b,
        float* __restrict__ out) {
    extern __shared__ char arena[];
    __hip_bfloat16* Actx = (__hip_bfloat16*)arena;            // [32][776]
    __hip_bfloat16* A2   = (__hip_bfloat16*)arena;            // [32][1544]
    __hip_bfloat16* Bs   = (__hip_bfloat16*)(arena + 98816);  // [768][36]
    __shared__ float wgt[32][4];
    __shared__ float stats[32][8][4];
    __shared__ float lnT[32][2], lnI[32][2], gpT[32][2], g01[32][2];

    const int tid = threadIdx.x;
    const int w = tid >> 6, lane = tid & 63;
    const int r0 = blockIdx.x * 32;
    const int n0w = w * 96;
    // per-lane output coords (MFMA C layout, m89-verified)
    const int colb = lane & 15, rowg = (lane >> 4) * 4;

    if (tid < 32) {                                   // softmax merge weights
        int gr = r0 + tid;
        float mv[4], lv[4];
        #pragma unroll
        for (int s = 0; s < 4; ++s) {
            mv[s] = ml[(gr * 4 + s) * 2];
            lv[s] = ml[(gr * 4 + s) * 2 + 1];
        }
        float mx = fmaxf(fmaxf(mv[0], mv[1]), fmaxf(mv[2], mv[3]));
        float f[4], gl = 0.f;
        #pragma unroll
        for (int s = 0; s < 4; ++s) { f[s] = __expf(mv[s] - mx); gl += f[s] * lv[s]; }
        float inv = 1.f / gl;
        #pragma unroll
        for (int s = 0; s < 4; ++s) wgt[tid][s] = f[s] * inv;
    }
    __syncthreads();

    // Phase A: ctx rows -> Actx (bf16)
    {
        const int rr = tid >> 4, c0 = (tid & 15) * 48;
        const int gr = r0 + rr;
        const float w0 = wgt[rr][0], w1 = wgt[rr][1], w2 = wgt[rr][2], w3 = wgt[rr][3];
        const float* p0 = &pacc[(size_t)(gr * 4 + 0) * HD + c0];
        const float* p1 = &pacc[(size_t)(gr * 4 + 1) * HD + c0];
        const float* p2 = &pacc[(size_t)(gr * 4 + 2) * HD + c0];
        const float* p3 = &pacc[(size_t)(gr * 4 + 3) * HD + c0];
        #pragma unroll
        for (int i = 0; i < 12; ++i) {
            float4 v = {0.f, 0.f, 0.f, 0.f};
            v = f4fma(w0, *(const float4*)(p0 + i * 4), v);
            v = f4fma(w1, *(const float4*)(p1 + i * 4), v);
            v = f4fma(w2, *(const float4*)(p2 + i * 4), v);
            v = f4fma(w3, *(const float4*)(p3 + i * 4), v);
            short4 pk;
            pk.x = f2bs(v.x); pk.y = f2bs(v.y); pk.z = f2bs(v.z); pk.w = f2bs(v.w);
            *(short4*)&Actx[(size_t)rr * ACTX_S + c0 + i * 4] = pk;
        }
    }
    __syncthreads();

    // GEMM1: icp = ctx @ Wtv  (acc1[2][6])
    f32x4 zero = {0.f, 0.f, 0.f, 0.f};
    f32x4 acc1[2][6];
    #pragma unroll
    for (int a = 0; a < 2; ++a)
        #pragma unroll
        for (int b2 = 0; b2 < 6; ++b2) acc1[a][b2] = zero;
    tail_gemm<768, ACTX_S>(Actx, Bs, Wtv, acc1, tid, w, lane);

    // icv = icp + btv + sum4 P ; per-row stats
    float icv[2][6][4];
    float btvv[6];
    #pragma unroll
    for (int fn = 0; fn < 6; ++fn) btvv[fn] = btv[n0w + fn * 16 + colb];
    #pragma unroll
    for (int fm = 0; fm < 2; ++fm)
        #pragma unroll
        for (int r = 0; r < 4; ++r) {
            int gr2 = r0 + fm * 16 + rowg + r;
            #pragma unroll
            for (int fn = 0; fn < 6; ++fn) {
                int col = n0w + fn * 16 + colb;
                float pv = 0.f;
                #pragma unroll
                for (int q = 0; q < 4; ++q)
                    pv += Pp[(size_t)q * BD * HD + (size_t)gr2 * HD + col];
                icv[fm][fn][r] = acc1[fm][fn][r] + btvv[fn] + pv;
            }
        }
    #pragma unroll
    for (int fm = 0; fm < 2; ++fm)
        #pragma unroll
        for (int r = 0; r < 4; ++r) {
            float s1 = 0.f, s2 = 0.f;
            #pragma unroll
            for (int fn = 0; fn < 6; ++fn) {
                float x = icv[fm][fn][r];
                s1 += x; s2 += x * x;
            }
            s1 = red16(s1); s2 = red16(s2);
            if (colb == 0) {
                int rl = fm * 16 + rowg + r;
                stats[rl][w][0] = s1; stats[rl][w][1] = s2;
            }
        }
    __syncthreads();
    if (tid < 32) {
        float s1 = 0.f, s2 = 0.f;
        #pragma unroll
        for (int q = 0; q < 8; ++q) { s1 += stats[tid][q][0]; s2 += stats[tid][q][1]; }
        float mu = s1 / HD, var = s2 / HD - mu * mu;
        lnI[tid][0] = mu; lnI[tid][1] = rsqrtf(var + EPSV);
    }
    __syncthreads();

    // Phase B pass1: tcv -> A2 bf16 (cols 0..768) + stats
    {
        const int rr = tid >> 4, c0 = (tid & 15) * 48;
        const int gr = r0 + rr;
        float s1 = 0.f, s2 = 0.f;
        #pragma unroll
        for (int i = 0; i < 12; ++i) {
            float4 v = *(const float4*)&tf[(size_t)gr * SD * HD + c0 + i * 4];
            #pragma unroll
            for (int q = 0; q < 4; ++q)
                v = f4sum(v, *(const float4*)&ivp[(size_t)q * BD * HD + (size_t)gr * HD + c0 + i * 4]);
            short4 pk;
            pk.x = f2bs(v.x); pk.y = f2bs(v.y); pk.z = f2bs(v.z); pk.w = f2bs(v.w);
            *(short4*)&A2[(size_t)rr * A2_S + c0 + i * 4] = pk;
            s1 += v.x + v.y + v.z + v.w;
            s2 += v.x*v.x + v.y*v.y + v.z*v.z + v.w*v.w;
        }
        s1 = red16(s1); s2 = red16(s2);
        if ((tid & 15) == 0) {
            float mu = s1 / HD, var = s2 / HD - mu * mu;
            lnT[rr][0] = mu; lnT[rr][1] = rsqrtf(var + EPSV);
        }
    }
    __syncthreads();

    // Phase B pass2: tcn (in place, bf16) + gate-t partials
    {
        const int rr = tid >> 4, c0 = (tid & 15) * 48;
        const float mu = lnT[rr][0], rs = lnT[rr][1];
        float z0 = 0.f, z1 = 0.f;
        for (int i = 0; i < 48; ++i) {
            int c = c0 + i;
            float tv = __bfloat162float(A2[(size_t)rr * A2_S + c]);
            float tcn = (tv - mu) * rs * tn_g[c] + tn_b[c];
            A2[(size_t)rr * A2_S + c] = __float2bfloat16(tcn);
            z0 = fmaf(tcn, Wg[c * 2 + 0], z0);
            z1 = fmaf(tcn, Wg[c * 2 + 1], z1);
        }
        z0 = red16(z0); z1 = red16(z1);
        if ((tid & 15) == 0) { gpT[rr][0] = z0; gpT[rr][1] = z1; }
    }
    // gate-i partials from icv regs
    {
        float ing[6], inb[6], wg0[6], wg1[6];
        #pragma unroll
        for (int fn = 0; fn < 6; ++fn) {
            int col = n0w + fn * 16 + colb;
            ing[fn] = in_g[col]; inb[fn] = in_b[col];
            wg0[fn] = Wg[(HD + col) * 2 + 0]; wg1[fn] = Wg[(HD + col) * 2 + 1];
        }
        #pragma unroll
        for (int fm = 0; fm < 2; ++fm)
            #pragma unroll
            for (int r = 0; r < 4; ++r) {
                int rl = fm * 16 + rowg + r;
                float mu = lnI[rl][0], rs = lnI[rl][1];
                float z0 = 0.f, z1 = 0.f;
                #pragma unroll
                for (int fn = 0; fn < 6; ++fn) {
                    float icn = (icv[fm][fn][r] - mu) * rs * ing[fn] + inb[fn];
                    z0 = fmaf(icn, wg0[fn], z0);
                    z1 = fmaf(icn, wg1[fn], z1);
                }
                z0 = red16(z0); z1 = red16(z1);
                if (colb == 0) { stats[rl][w][2] = z0; stats[rl][w][3] = z1; }
            }
    }
    __syncthreads();
    if (tid < 32) {
        float z0 = gpT[tid][0] + bg[0], z1 = gpT[tid][1] + bg[1];
        #pragma unroll
        for (int q = 0; q < 8; ++q) { z0 += stats[tid][q][2]; z1 += stats[tid][q][3]; }
        float mx = fmaxf(z0, z1);
        float e0 = __expf(z0 - mx), e1 = __expf(z1 - mx);
        float inv = 1.f / (e0 + e1);
        g01[tid][0] = e0 * inv; g01[tid][1] = e1 * inv;
    }
    __syncthreads();

    // scale tcn half by g0; write icn*g1 half
    {
        const int rr = tid >> 4, c0 = (tid & 15) * 48;
        const float g0 = g01[rr][0];
        for (int i = 0; i < 48; ++i) {
            int c = c0 + i;
            float v = __bfloat162float(A2[(size_t)rr * A2_S + c]) * g0;
            A2[(size_t)rr * A2_S + c] = __float2bfloat16(v);
        }
    }
    {
        float ing[6], inb[6];
        #pragma unroll
        for (int fn = 0; fn < 6; ++fn) {
            int col = n0w + fn * 16 + colb;
            ing[fn] = in_g[col]; inb[fn] = in_b[col];
        }
        #pragma unroll
        for (int fm = 0; fm < 2; ++fm)
            #pragma unroll
            for (int r = 0; r < 4; ++r) {
                int rl = fm * 16 + rowg + r;
                float mu = lnI[rl][0], rs = lnI[rl][1], g1 = g01[rl][1];
                #pragma unroll
                for (int fn = 0; fn < 6; ++fn) {
                    int col = n0w + fn * 16 + colb;
                    float icn = (icv[fm][fn][r] - mu) * rs * ing[fn] + inb[fn];
                    A2[(size_t)rl * A2_S + HD + col] = __float2bfloat16(icn * g1);
                }
            }
    }
    __syncthreads();

    // GEMM2: yb = wtd @ Wf
    f32x4 acc2[2][6];
    #pragma unroll
    for (int a = 0; a < 2; ++a)
        #pragma unroll
        for (int b2 = 0; b2 < 6; ++b2) acc2[a][b2] = zero;
    tail_gemm<1536, A2_S>(A2, Bs, Wf, acc2, tid, w, lane);

    // final LN + gelu
    float bffv[6];
    #pragma unroll
    for (int fn = 0; fn < 6; ++fn) bffv[fn] = bff[n0w + fn * 16 + colb];
    float yv[2][6][4];
    #pragma unroll
    for (int fm = 0; fm < 2; ++fm)
        #pragma unroll
        for (int r = 0; r < 4; ++r) {
            float s1 = 0.f, s2 = 0.f;
            #pragma unroll
            for (int fn = 0; fn < 6; ++fn) {
                float x = acc2[fm][fn][r] + bffv[fn];
                yv[fm][fn][r] = x;
                s1 += x; s2 += x * x;
            }
            s1 = red16(s1); s2 = red16(s2);
            if (colb == 0) {
                int rl = fm * 16 + rowg + r;
                stats[rl][w][0] = s1; stats[rl][w][1] = s2;
            }
        }
    __syncthreads();
    if (tid < 32) {
        float s1 = 0.f, s2 = 0.f;
        #pragma unroll
        for (int q = 0; q < 8; ++q) { s1 += stats[tid][q][0]; s2 += stats[tid][q][1]; }
        float mu = s1 / HD, var = s2 / HD - mu * mu;
        lnT[tid][0] = mu; lnT[tid][1] = rsqrtf(var + EPSV);
    }
    __syncthreads();
    {
        float fg[6], fb[6];
        #pragma unroll
        for (int fn = 0; fn < 6; ++fn) {
            int col = n0w + fn * 16 + colb;
            fg[fn] = fn_g[col]; fb[fn] = fn_b[col];
        }
        #pragma unroll
        for (int fm = 0; fm < 2; ++fm)
            #pragma unroll
            for (int r = 0; r < 4; ++r) {
                int rl = fm * 16 + rowg + r;
                int gr2 = r0 + rl;
                float mu = lnT[rl][0], rs = lnT[rl][1];
                #pragma unroll
                for (int fn = 0; fn < 6; ++fn) {
                    int col = n0w + fn * 16 + colb;
                    float x = (yv[fm][fn][r] - mu) * rs * fg[fn] + fb[fn];
                    float g = 0.5f * x * (1.f + erff(x * 0.7071067811865476f));
                    out[(size_t)gr2 * HD + col] = g;
                }
            }
    }
}

// ---------------------------------------------------------------------------
// Fallback tail kernels (round-7 path, proven)
// ---------------------------------------------------------------------------
__global__ __launch_bounds__(256) void gemm_ctxv(const float* __restrict__ pacc,
                                                 const float* __restrict__ ml,
                                                 const float* __restrict__ Wtv,
                                                 const float* __restrict__ btv,
                                                 float* __restrict__ icpp) {
    __shared__ GemmSmem smem;
    __shared__ float wgt[64][SPLIT];
    const int tid = threadIdx.x;
    const int arow = tid >> 2, akc = (tid & 3) * 8;
    const int bkk  = tid >> 3, bnc = (tid & 7) * 8;
    const int part = blockIdx.x / 48, tile = blockIdx.x % 48;
    const int m0 = (tile / 12) * 64, n0 = (tile % 12) * 64, kbeg = part * 192;

    if (tid < 64) {
        const int gr = m0 + tid;
        float mv[SPLIT], lv[SPLIT];
        #pragma unroll
        for (int s = 0; s < SPLIT; ++s) {
            mv[s] = ml[(gr * SPLIT + s) * 2];
            lv[s] = ml[(gr * SPLIT + s) * 2 + 1];
        }
        float mx = fmaxf(fmaxf(mv[0], mv[1]), fmaxf(mv[2], mv[3]));
        float f[SPLIT], gl = 0.f;
        #pragma unroll
        for (int s = 0; s < SPLIT; ++s) { f[s] = __expf(mv[s] - mx); gl += f[s] * lv[s]; }
        float inv = 1.f / gl;
        #pragma unroll
        for (int s = 0; s < SPLIT; ++s) wgt[tid][s] = f[s] * inv;
    }
    __syncthreads();

    const float* ap = &pacc[(size_t)(m0 + arow) * SPLIT * HD + kbeg + akc];
    auto al = [&](int t, float4& v0, float4& v1_) {
        const float* p = ap + t * 32;
        float4 x0 = {0.f, 0.f, 0.f, 0.f}, x1 = {0.f, 0.f, 0.f, 0.f};
        #pragma unroll
        for (int s = 0; s < SPLIT; ++s) {
            float wv = wgt[arow][s];
            const float* r = p + (size_t)s * HD;
            x0 = f4fma(wv, *(const float4*)r, x0);
            x1 = f4fma(wv, *(const float4*)(r + 4), x1);
        }
        v0 = x0; v1_ = x1;
    };
    const float* bq = &Wtv[(size_t)(kbeg + bkk) * HD + n0 + bnc];
    auto bl = [&](int t, float4& v0, float4& v1_) {
        const float* p = bq + (size_t)t * 32 * HD;
        v0 = *(const float4*)p; v1_ = *(const float4*)(p + 4);
    };
    gemm_core<false>(smem, al, bl, part == 0 ? btv : nullptr,
                     icpp + (size_t)part * BD * HD, HD, m0, n0, 6);
}

__global__ __launch_bounds__(256) void gemm_wf(const float* __restrict__ wtd,
                                               const float* __restrict__ Wf,
                                               const float* __restrict__ bf,
                                               float* __restrict__ ybp) {
    __shared__ GemmSmem smem;
    const int tid = threadIdx.x;
    const int arow = tid >> 2, akc = (tid & 3) * 8;
    const int bkk  = tid >> 3, bnc = (tid & 7) * 8;
    const int part = blockIdx.x / 48, tile = blockIdx.x % 48;
    const int m0 = (tile / 12) * 64, n0 = (tile % 12) * 64, kbeg = part * 192;
    const float* ap = &wtd[(size_t)(m0 + arow) * TWOH + kbeg + akc];
    const float* bq = &Wf[(size_t)(kbeg + bkk) * HD + n0 + bnc];
    auto al = [&](int t, float4& v0, float4& v1_) {
        const float* p = ap + t * 32;
        v0 = *(const float4*)p; v1_ = *(const float4*)(p + 4);
    };
    auto bl = [&](int t, float4& v0, float4& v1_) {
        const float* p = bq + (size_t)t * 32 * HD;
        v0 = *(const float4*)p; v1_ = *(const float4*)(p + 4);
    };
    gemm_core<false>(smem, al, bl, part == 0 ? bf : nullptr,
                     ybp + (size_t)part * BD * HD, HD, m0, n0, 6);
}

__device__ __forceinline__ float block_sum256(float v, float* red, int w, int lane) {
    #pragma unroll
    for (int off = 32; off > 0; off >>= 1) v += __shfl_xor(v, off);
    __syncthreads();
    if (lane == 0) red[w] = v;
    __syncthreads();
    return red[0] + red[1] + red[2] + red[3];
}

__global__ __launch_bounds__(256) void fuse_small(const float* __restrict__ icpp,
                                                  const float* __restrict__ Pp,
                                                  const float* __restrict__ ivp,
                                                  const float* __restrict__ tf,
                                                  const float* __restrict__ in_g,
                                                  const float* __restrict__ in_b,
                                                  const float* __restrict__ tn_g,
                                                  const float* __restrict__ tn_b,
                                                  const float* __restrict__ Wg,
                                                  const float* __restrict__ bg,
                                                  float* __restrict__ wtd) {
    const int b = blockIdx.x, tid = threadIdx.x;
    const int w = tid >> 6, lane = tid & 63;
    __shared__ float red[4];
    float icv[3], tcv[3];
    #pragma unroll
    for (int j = 0; j < 3; ++j) {
        int c = j * 256 + tid;
        float pv = 0.f, ic = 0.f, iv = 0.f;
        #pragma unroll
        for (int q = 0; q < 4; ++q) {
            pv += Pp[(size_t)q * BD * HD + b * HD + c];
            ic += icpp[(size_t)q * BD * HD + b * HD + c];
            iv += ivp[(size_t)q * BD * HD + b * HD + c];
        }
        icv[j] = ic + pv;
        tcv[j] = iv + tf[(size_t)b * SD * HD + c];
    }
    float s_i  = block_sum256(icv[0] + icv[1] + icv[2], red, w, lane);
    float ss_i = block_sum256(icv[0]*icv[0] + icv[1]*icv[1] + icv[2]*icv[2], red, w, lane);
    float s_t  = block_sum256(tcv[0] + tcv[1] + tcv[2], red, w, lane);
    float ss_t = block_sum256(tcv[0]*tcv[0] + tcv[1]*tcv[1] + tcv[2]*tcv[2], red, w, lane);
    const float invh = 1.f / HD;
    float mu_i = s_i * invh, var_i = ss_i * invh - mu_i * mu_i;
    float mu_t = s_t * invh, var_t = ss_t * invh - mu_t * mu_t;
    float rs_i = rsqrtf(var_i + EPSV), rs_t = rsqrtf(var_t + EPSV);
    float icn[3], tcn[3];
    #pragma unroll
    for (int j = 0; j < 3; ++j) {
        int c = j * 256 + tid;
        icn[j] = (icv[j] - mu_i) * rs_i * in_g[c] + in_b[c];
        tcn[j] = (tcv[j] - mu_t) * rs_t * tn_g[c] + tn_b[c];
    }
    float z0p = 0.f, z1p = 0.f;
    #pragma unroll
    for (int j = 0; j < 3; ++j) {
        int c = j * 256 + tid;
        z0p += tcn[j] * Wg[c * 2 + 0] + icn[j] * Wg[(HD + c) * 2 + 0];
        z1p += tcn[j] * Wg[c * 2 + 1] + icn[j] * Wg[(HD + c) * 2 + 1];
    }
    float z0 = block_sum256(z0p, red, w, lane) + bg[0];
    float z1 = block_sum256(z1p, red, w, lane) + bg[1];
    float mx = fmaxf(z0, z1);
    float e0 = __expf(z0 - mx), e1 = __expf(z1 - mx);
    float inv = 1.f / (e0 + e1);
    float g0 = e0 * inv, g1 = e1 * inv;
    #pragma unroll
    for (int j = 0; j < 3; ++j) {
        int c = j * 256 + tid;
        wtd[(size_t)b * TWOH + c]      = tcn[j] * g0;
        wtd[(size_t)b * TWOH + HD + c] = icn[j] * g1;
    }
}

__global__ __launch_bounds__(256) void final_ln_gelu(const float* __restrict__ ybp,
                                                     const float* __restrict__ fn_g,
                                                     const float* __restrict__ fn_b,
                                                     float* __restrict__ out) {
    const int b = blockIdx.x, tid = threadIdx.x;
    const int w = tid >> 6, lane = tid & 63;
    __shared__ float red[4];
    float v[3];
    #pragma unroll
    for (int j = 0; j < 3; ++j) {
        int c = j * 256 + tid;
        float x = 0.f;
        #pragma unroll
        for (int q = 0; q < 8; ++q) x += ybp[(size_t)q * BD * HD + b * HD + c];
        v[j] = x;
    }
    float s  = block_sum256(v[0] + v[1] + v[2], red, w, lane);
    float ss = block_sum256(v[0]*v[0] + v[1]*v[1] + v[2]*v[2], red, w, lane);
    const float invh = 1.f / HD;
    float mu = s * invh, var = ss * invh - mu * mu;
    float rs = rsqrtf(var + EPSV);
    #pragma unroll
    for (int j = 0; j < 3; ++j) {
        int c = j * 256 + tid;
        float x = (v[j] - mu) * rs * fn_g[c] + fn_b[c];
        float g = 0.5f * x * (1.f + erff(x * 0.7071067811865476f));
        out[b * HD + c] = g;
    }
}

// ---------------------------------------------------------------------------
extern "C" void kernel_launch(void* const* d_in, const int* in_sizes, int n_in,
                              void* d_out, int out_size, void* d_ws, size_t ws_size,
                              hipStream_t stream) {
    const float* tf   = (const float*)d_in[0];
    const float* imgf = (const float*)d_in[1];
    const float* Wp   = (const float*)d_in[2];
    const float* bp   = (const float*)d_in[3];
    const float* Wiv  = (const float*)d_in[8];
    const float* biv  = (const float*)d_in[9];
    const float* Wiq  = (const float*)d_in[10];
    const float* biq  = (const float*)d_in[11];
    const float* Wtk  = (const float*)d_in[12];
    const float* Wtv  = (const float*)d_in[14];
    const float* btv  = (const float*)d_in[15];
    const float* tn_g = (const float*)d_in[16];
    const float* tn_b = (const float*)d_in[17];
    const float* in_g = (const float*)d_in[18];
    const float* in_b = (const float*)d_in[19];
    const float* Wf   = (const float*)d_in[20];
    const float* bff  = (const float*)d_in[21];
    const float* fn_g = (const float*)d_in[22];
    const float* fn_b = (const float*)d_in[23];
    const float* Wg   = (const float*)d_in[24];
    const float* bg   = (const float*)d_in[25];

    float* ws    = (float*)d_ws;
    float* Pp    = ws;                      // 4 * B*H
    float* Wqkp  = Pp    + 4 * BD * HD;     // 4 * H*H
    float* v1    = Wqkp  + 4 * HD * HD;     // H
    float* qtp   = v1    + HD;              // 4 * B*H
    float* ivp   = qtp   + 4 * BD * HD;     // 4 * B*H
    float* icpp  = ivp   + 4 * BD * HD;     // 4 * B*H (fallback)
    float* ybp   = icpp  + 4 * BD * HD;     // 8 * B*H (fallback)
    float* wtd   = ybp   + 8 * BD * HD;     // B*2H    (fallback)
    float* pacc  = wtd   + BD * TWOH;       // B*SPLIT*H
    float* ml    = pacc  + (size_t)BD * SPLIT * HD;  // B*SPLIT*2

    stage1<<<780, 256, 0, stream>>>(imgf, Wp, bp, Wiq, Wtk, biq, Pp, Wqkp, v1);
    stage2<<<384, 256, 0, stream>>>(Pp, Wqkp, v1, Wiv, biv, qtp, ivp);
    stream_attn<<<BD * SPLIT, 256, 0, stream>>>(tf, qtp, pacc, ml);

    (void)hipFuncSetAttribute((const void*)tail8,
                              hipFuncAttributeMaxDynamicSharedMemorySize,
                              TAIL_LDS_BYTES);
    tail8<<<8, 512, TAIL_LDS_BYTES, stream>>>(pacc, ml, Wtv, btv, Pp, ivp, tf,
                                              in_g, in_b, tn_g, tn_b, Wg, bg,
                                              Wf, bff, fn_g, fn_b, (float*)d_out);
    if (hipGetLastError() != hipSuccess) {
        // fallback: proven round-7 tail
        gemm_ctxv<<<192, 256, 0, stream>>>(pacc, ml, Wtv, btv, icpp);
        fuse_small<<<BD, 256, 0, stream>>>(icpp, Pp, ivp, tf, in_g, in_b,
                                           tn_g, tn_b, Wg, bg, wtd);
        gemm_wf<<<384, 256, 0, stream>>>(wtd, Wf, bff, ybp);
        final_ln_gelu<<<BD, 256, 0, stream>>>(ybp, fn_g, fn_b, (float*)d_out);
    }
}

// Round 10
// 469.259 us; speedup vs baseline: 1.3332x; 1.3332x over previous
//
#include <hip/hip_runtime.h>
#include <hip/hip_bf16.h>

// Problem constants
#define BD   256
#define SD   512
#define HD   768
#define IMGD 2048
#define TWOH 1536
constexpr float EPSV  = 1e-5f;
constexpr float SCALE = 0.036084391824351615f;  // 1/sqrt(768)
constexpr int   SPLIT = 4;
constexpr int   SBLK  = SD / SPLIT;             // 128 rows per slice
#define GRIDN 512u   // persistent grid: 2 blocks/CU via launch_bounds(256,2)

typedef __attribute__((ext_vector_type(8))) short short8;
typedef __attribute__((ext_vector_type(4))) float f32x4;

__device__ __forceinline__ short f2bs(float x) {
    __hip_bfloat16 h = __float2bfloat16(x);
    return __builtin_bit_cast(short, h);
}
__device__ __forceinline__ float4 f4sum(float4 a, float4 b) {
    return make_float4(a.x + b.x, a.y + b.y, a.z + b.z, a.w + b.w);
}
__device__ __forceinline__ float4 f4fma(float s, float4 v, float4 acc) {
    return make_float4(fmaf(s, v.x, acc.x), fmaf(s, v.y, acc.y),
                       fmaf(s, v.z, acc.z), fmaf(s, v.w, acc.w));
}

struct GemmSmem {
    __hip_bfloat16 As[2][64][40];
    __hip_bfloat16 Bs[2][64][40];
};

// ---------------------------------------------------------------------------
// Monotone counting grid barrier, round-indexed targets. REQUIRES cnt == 0 at
// kernel start — guaranteed by hipMemsetAsync on the same stream (captured as
// a graph node, so it re-runs before every replay). Device-scope atomics
// (cross-XCD safe, m20) + __threadfence release/acquire. A ~100ms realtime
// watchdog converts any residual hang into a wrong-answer signal instead of
// a 600s timeout (legit phase waits are <1ms; never triggers when healthy).
// ---------------------------------------------------------------------------
__device__ __forceinline__ void gbar(unsigned* cnt, unsigned round) {
    __syncthreads();
    if (threadIdx.x == 0) {
        __threadfence();                         // release our global writes
        atomicAdd(cnt, 1u);                      // device-scope by default
        const unsigned target = round * GRIDN;
        unsigned long long t0 = __builtin_amdgcn_s_memrealtime();
        while (__hip_atomic_load(cnt, __ATOMIC_RELAXED,
                                 __HIP_MEMORY_SCOPE_AGENT) < target) {
            __builtin_amdgcn_s_sleep(8);
            if (__builtin_amdgcn_s_memrealtime() - t0 > 10000000ull) break;
        }
        __threadfence();                         // acquire others' writes
    }
    __syncthreads();
}

// ---------------------------------------------------------------------------
// 64x64-tile GEMM core (verified since r4): BK=32, double LDS buffer,
// depth-2 register prefetch. Lambdas deliver two float4 per thread per tile.
// ---------------------------------------------------------------------------
template<bool TRANSB, class AF, class BF>
__device__ __forceinline__ void gemm_core(GemmSmem& smem, AF aload, BF bload,
        const float* __restrict__ bias, float* __restrict__ C,
        int N, int m0, int n0, int NT) {
    const int tid  = threadIdx.x;
    const int w    = tid >> 6, lane = tid & 63;
    const int wr   = w >> 1,  wc   = w & 1;
    const int rsel = lane & 15, ks = (lane >> 4) * 8;
    const int arow = tid >> 2, akc = (tid & 3) * 8;
    const int bkk  = tid >> 3, bnc = (tid & 7) * 8;

    float4 a0v[2], a1v[2], b0v[2], b1v[2];

    auto issue = [&](int slot, int t) {
        aload(t, a0v[slot], a1v[slot]);
        bload(t, b0v[slot], b1v[slot]);
    };
    auto commit = [&](int buf, int slot) {
        short8 pk;
        pk[0]=f2bs(a0v[slot].x); pk[1]=f2bs(a0v[slot].y);
        pk[2]=f2bs(a0v[slot].z); pk[3]=f2bs(a0v[slot].w);
        pk[4]=f2bs(a1v[slot].x); pk[5]=f2bs(a1v[slot].y);
        pk[6]=f2bs(a1v[slot].z); pk[7]=f2bs(a1v[slot].w);
        *(short8*)&smem.As[buf][arow][akc] = pk;
        if (TRANSB) {
            short8 qk;
            qk[0]=f2bs(b0v[slot].x); qk[1]=f2bs(b0v[slot].y);
            qk[2]=f2bs(b0v[slot].z); qk[3]=f2bs(b0v[slot].w);
            qk[4]=f2bs(b1v[slot].x); qk[5]=f2bs(b1v[slot].y);
            qk[6]=f2bs(b1v[slot].z); qk[7]=f2bs(b1v[slot].w);
            *(short8*)&smem.Bs[buf][arow][akc] = qk;
        } else {
            smem.Bs[buf][bnc + 0][bkk] = __float2bfloat16(b0v[slot].x);
            smem.Bs[buf][bnc + 1][bkk] = __float2bfloat16(b0v[slot].y);
            smem.Bs[buf][bnc + 2][bkk] = __float2bfloat16(b0v[slot].z);
            smem.Bs[buf][bnc + 3][bkk] = __float2bfloat16(b0v[slot].w);
            smem.Bs[buf][bnc + 4][bkk] = __float2bfloat16(b1v[slot].x);
            smem.Bs[buf][bnc + 5][bkk] = __float2bfloat16(b1v[slot].y);
            smem.Bs[buf][bnc + 6][bkk] = __float2bfloat16(b1v[slot].z);
            smem.Bs[buf][bnc + 7][bkk] = __float2bfloat16(b1v[slot].w);
        }
    };

    f32x4 zero = {0.f, 0.f, 0.f, 0.f};
    f32x4 acc[2][2] = {{zero, zero}, {zero, zero}};

    issue(0, 0);
    commit(0, 0);
    if (NT > 1) issue(1, 1);
    __syncthreads();

    for (int t = 0; t < NT; ++t) {
        const int cur = t & 1;
        short8 A0 = *(const short8*)&smem.As[cur][wr * 32 + rsel][ks];
        short8 A1 = *(const short8*)&smem.As[cur][wr * 32 + 16 + rsel][ks];
        short8 B0 = *(const short8*)&smem.Bs[cur][wc * 32 + rsel][ks];
        short8 B1 = *(const short8*)&smem.Bs[cur][wc * 32 + 16 + rsel][ks];
        if (t + 1 < NT) commit(cur ^ 1, (t + 1) & 1);
        if (t + 2 < NT) issue(cur, t + 2);
        acc[0][0] = __builtin_amdgcn_mfma_f32_16x16x32_bf16(A0, B0, acc[0][0], 0, 0, 0);
        acc[0][1] = __builtin_amdgcn_mfma_f32_16x16x32_bf16(A0, B1, acc[0][1], 0, 0, 0);
        acc[1][0] = __builtin_amdgcn_mfma_f32_16x16x32_bf16(A1, B0, acc[1][0], 0, 0, 0);
        acc[1][1] = __builtin_amdgcn_mfma_f32_16x16x32_bf16(A1, B1, acc[1][1], 0, 0, 0);
        __syncthreads();
    }

    // C/D layout: col = lane&15, row = (lane>>4)*4 + reg  [m89-verified]
    const int colb = lane & 15, rowb = (lane >> 4) * 4;
    #pragma unroll
    for (int fm = 0; fm < 2; ++fm)
        #pragma unroll
        for (int fn = 0; fn < 2; ++fn)
            #pragma unroll
            for (int r = 0; r < 4; ++r) {
                int row = m0 + wr * 32 + fm * 16 + rowb + r;
                int col = n0 + wc * 32 + fn * 16 + colb;
                float v = acc[fm][fn][r];
                if (bias) v += bias[col];
                C[(size_t)row * N + col] = v;
            }
}

// ---------------------------------------------------------------------------
// Phase bodies — round-7 kernels verbatim, parameterized by virtual block id.
// ---------------------------------------------------------------------------
__device__ void ph_stage1(GemmSmem& smem, int blk,
        const float* __restrict__ imgf, const float* __restrict__ Wp,
        const float* __restrict__ bp, const float* __restrict__ Wiq,
        const float* __restrict__ Wtk, const float* __restrict__ biq,
        float* __restrict__ Pp, float* __restrict__ Wqkp, float* __restrict__ v1) {
    const int tid = threadIdx.x;
    const int arow = tid >> 2, akc = (tid & 3) * 8;
    const int bkk  = tid >> 3, bnc = (tid & 7) * 8;
    if (blk < 192) {
        const int part = blk / 48, tile = blk % 48;
        const int m0 = (tile / 12) * 64, n0 = (tile % 12) * 64, kbeg = part * 512;
        const float* ap = &imgf[(size_t)(m0 + arow) * IMGD + kbeg + akc];
        const float* bq = &Wp[(size_t)(kbeg + bkk) * HD + n0 + bnc];
        auto al = [&](int t, float4& v0, float4& v1_) {
            const float* p = ap + t * 32;
            v0 = *(const float4*)p; v1_ = *(const float4*)(p + 4);
        };
        auto bl = [&](int t, float4& v0, float4& v1_) {
            const float* p = bq + (size_t)t * 32 * HD;
            v0 = *(const float4*)p; v1_ = *(const float4*)(p + 4);
        };
        gemm_core<false>(smem, al, bl, part == 0 ? bp : nullptr,
                         Pp + (size_t)part * BD * HD, HD, m0, n0, 16);
    } else if (blk < 768) {
        const int b2 = blk - 192, part = b2 / 144, tile = b2 % 144;
        const int m0 = (tile / 12) * 64, n0 = (tile % 12) * 64, kbeg = part * 192;
        const float* ap = &Wiq[(size_t)(m0 + arow) * HD + kbeg + akc];
        const float* bq = &Wtk[(size_t)(n0 + arow) * HD + kbeg + akc];
        auto al = [&](int t, float4& v0, float4& v1_) {
            const float* p = ap + t * 32;
            v0 = *(const float4*)p; v1_ = *(const float4*)(p + 4);
        };
        auto bl = [&](int t, float4& v0, float4& v1_) {
            const float* p = bq + t * 32;
            v0 = *(const float4*)p; v1_ = *(const float4*)(p + 4);
        };
        gemm_core<true>(smem, al, bl, nullptr,
                        Wqkp + (size_t)part * HD * HD, HD, m0, n0, 6);
    } else if (blk < 780) {
        const int b2 = blk - 768;
        const int w = tid >> 6, lane = tid & 63;
        float bq[12];
        #pragma unroll
        for (int c = 0; c < 12; ++c) bq[c] = biq[c * 64 + lane];
        const int d0 = b2 * 64 + w * 16;
        for (int i = 0; i < 16; ++i) {
            const float* row = &Wtk[(size_t)(d0 + i) * HD];
            float p = 0.f;
            #pragma unroll
            for (int c = 0; c < 12; ++c) p = fmaf(row[c * 64 + lane], bq[c], p);
            #pragma unroll
            for (int off = 32; off > 0; off >>= 1) p += __shfl_xor(p, off);
            if (lane == 0) v1[d0 + i] = p;
        }
    }
}

__device__ void ph_stage2(GemmSmem& smem, int blk,
        const float* __restrict__ Pp, const float* __restrict__ Wqkp,
        const float* __restrict__ v1, const float* __restrict__ Wiv,
        const float* __restrict__ biv, float* __restrict__ qtp,
        float* __restrict__ ivp) {
    const int tid = threadIdx.x;
    const int arow = tid >> 2, akc = (tid & 3) * 8;
    const int bkk  = tid >> 3, bnc = (tid & 7) * 8;
    const bool isqt = blk < 192;
    const int b2 = isqt ? blk : blk - 192;
    const int part = b2 / 48, tile = b2 % 48;
    const int m0 = (tile / 12) * 64, n0 = (tile % 12) * 64, kbeg = part * 192;

    const float* ap = &Pp[(size_t)(m0 + arow) * HD + kbeg + akc];
    auto al = [&](int t, float4& v0, float4& v1_) {
        const float* p = ap + t * 32;
        float4 x0 = *(const float4*)p, x1 = *(const float4*)(p + 4);
        #pragma unroll
        for (int q = 1; q < 4; ++q) {
            const float* r = p + (size_t)q * BD * HD;
            x0 = f4sum(x0, *(const float4*)r);
            x1 = f4sum(x1, *(const float4*)(r + 4));
        }
        v0 = x0; v1_ = x1;
    };
    if (isqt) {
        const float* bq = &Wqkp[(size_t)(kbeg + bkk) * HD + n0 + bnc];
        auto bl = [&](int t, float4& v0, float4& v1_) {
            const float* p = bq + (size_t)t * 32 * HD;
            float4 x0 = *(const float4*)p, x1 = *(const float4*)(p + 4);
            #pragma unroll
            for (int q = 1; q < 4; ++q) {
                const float* r = p + (size_t)q * HD * HD;
                x0 = f4sum(x0, *(const float4*)r);
                x1 = f4sum(x1, *(const float4*)(r + 4));
            }
            v0 = x0; v1_ = x1;
        };
        gemm_core<false>(smem, al, bl, part == 0 ? v1 : nullptr,
                         qtp + (size_t)part * BD * HD, HD, m0, n0, 6);
    } else {
        const float* bq = &Wiv[(size_t)(kbeg + bkk) * HD + n0 + bnc];
        auto bl = [&](int t, float4& v0, float4& v1_) {
            const float* p = bq + (size_t)t * 32 * HD;
            v0 = *(const float4*)p; v1_ = *(const float4*)(p + 4);
        };
        gemm_core<false>(smem, al, bl, part == 0 ? biv : nullptr,
                         ivp + (size_t)part * BD * HD, HD, m0, n0, 6);
    }
}

__device__ void ph_attn(float (*sacc)[HD], float* sm_, float* sl_, int item,
        const float* __restrict__ tf, const float* __restrict__ qtp,
        float* __restrict__ pacc, float* __restrict__ ml) {
    const int tid = threadIdx.x, w = tid >> 6, lane = tid & 63;
    const int b = item >> 2, sl = item & 3;

    float q[12];
    {
        const float* qp = &qtp[b * HD];
        #pragma unroll
        for (int c = 0; c < 3; ++c) {
            float4 v = *(const float4*)&qp[c * 256 + 4 * lane];
            #pragma unroll
            for (int p = 1; p < 4; ++p)
                v = f4sum(v, *(const float4*)&qp[(size_t)p * BD * HD + c * 256 + 4 * lane]);
            q[c*4+0] = v.x; q[c*4+1] = v.y; q[c*4+2] = v.z; q[c*4+3] = v.w;
        }
    }
    float a[12];
    #pragma unroll
    for (int j = 0; j < 12; ++j) a[j] = 0.f;
    float m = -INFINITY, l = 0.f;

    const int r0 = sl * SBLK + w * (SBLK / 4);
    const float* base = &tf[((size_t)b * SD + r0) * HD];

    float tA[12], tB[12];
    auto loadrow = [&](int i, float* t) {
        const float* row = base + (size_t)i * HD;
        #pragma unroll
        for (int c = 0; c < 3; ++c) {
            float4 v = *(const float4*)&row[c * 256 + 4 * lane];
            t[c*4+0] = v.x; t[c*4+1] = v.y; t[c*4+2] = v.z; t[c*4+3] = v.w;
        }
    };
    auto process = [&](const float* t) {
        float p = 0.f;
        #pragma unroll
        for (int j = 0; j < 12; ++j) p = fmaf(t[j], q[j], p);
        #pragma unroll
        for (int off = 32; off > 0; off >>= 1) p += __shfl_xor(p, off);
        float score = p * SCALE;
        float mn = fmaxf(m, score);
        float eo = __expf(m - mn);
        float en = __expf(score - mn);
        l = fmaf(l, eo, en);
        #pragma unroll
        for (int j = 0; j < 12; ++j) a[j] = fmaf(a[j], eo, en * t[j]);
        m = mn;
    };

    loadrow(0, tA);
    for (int i = 0; i < 32; i += 2) {
        loadrow(i + 1, tB);
        process(tA);
        if (i + 2 < 32) loadrow(i + 2, tA);
        process(tB);
    }

    #pragma unroll
    for (int c = 0; c < 3; ++c)
        #pragma unroll
        for (int j = 0; j < 4; ++j)
            sacc[w][c * 256 + 4 * lane + j] = a[c * 4 + j];
    if (lane == 0) { sm_[w] = m; sl_[w] = l; }
    __syncthreads();
    float gm = fmaxf(fmaxf(sm_[0], sm_[1]), fmaxf(sm_[2], sm_[3]));
    float f0 = __expf(sm_[0] - gm), f1 = __expf(sm_[1] - gm);
    float f2 = __expf(sm_[2] - gm), f3 = __expf(sm_[3] - gm);
    float gl = f0 * sl_[0] + f1 * sl_[1] + f2 * sl_[2] + f3 * sl_[3];
    float* outp = &pacc[(size_t)item * HD];
    #pragma unroll
    for (int jj = 0; jj < 3; ++jj) {
        int c = jj * 256 + tid;
        outp[c] = f0 * sacc[0][c] + f1 * sacc[1][c] + f2 * sacc[2][c] + f3 * sacc[3][c];
    }
    if (tid == 0) { ml[item * 2] = gm; ml[item * 2 + 1] = gl; }
    __syncthreads();   // sacc reused by next item on this block
}

__device__ void ph_ctxv(GemmSmem& smem, float (*wgt)[SPLIT], int blk,
        const float* __restrict__ pacc, const float* __restrict__ ml,
        const float* __restrict__ Wtv, const float* __restrict__ btv,
        float* __restrict__ icpp) {
    const int tid = threadIdx.x;
    const int arow = tid >> 2, akc = (tid & 3) * 8;
    const int bkk  = tid >> 3, bnc = (tid & 7) * 8;
    const int part = blk / 48, tile = blk % 48;
    const int m0 = (tile / 12) * 64, n0 = (tile % 12) * 64, kbeg = part * 192;

    if (tid < 64) {
        const int gr = m0 + tid;
        float mv[SPLIT], lv[SPLIT];
        #pragma unroll
        for (int s = 0; s < SPLIT; ++s) {
            mv[s] = ml[(gr * SPLIT + s) * 2];
            lv[s] = ml[(gr * SPLIT + s) * 2 + 1];
        }
        float mx = fmaxf(fmaxf(mv[0], mv[1]), fmaxf(mv[2], mv[3]));
        float f[SPLIT], gl = 0.f;
        #pragma unroll
        for (int s = 0; s < SPLIT; ++s) { f[s] = __expf(mv[s] - mx); gl += f[s] * lv[s]; }
        float inv = 1.f / gl;
        #pragma unroll
        for (int s = 0; s < SPLIT; ++s) wgt[tid][s] = f[s] * inv;
    }
    __syncthreads();

    const float* ap = &pacc[(size_t)(m0 + arow) * SPLIT * HD + kbeg + akc];
    auto al = [&](int t, float4& v0, float4& v1_) {
        const float* p = ap + t * 32;
        float4 x0 = {0.f, 0.f, 0.f, 0.f}, x1 = {0.f, 0.f, 0.f, 0.f};
        #pragma unroll
        for (int s = 0; s < SPLIT; ++s) {
            float wv = wgt[arow][s];
            const float* r = p + (size_t)s * HD;
            x0 = f4fma(wv, *(const float4*)r, x0);
            x1 = f4fma(wv, *(const float4*)(r + 4), x1);
        }
        v0 = x0; v1_ = x1;
    };
    const float* bq = &Wtv[(size_t)(kbeg + bkk) * HD + n0 + bnc];
    auto bl = [&](int t, float4& v0, float4& v1_) {
        const float* p = bq + (size_t)t * 32 * HD;
        v0 = *(const float4*)p; v1_ = *(const float4*)(p + 4);
    };
    gemm_core<false>(smem, al, bl, part == 0 ? btv : nullptr,
                     icpp + (size_t)part * BD * HD, HD, m0, n0, 6);
}

__device__ void ph_wf(GemmSmem& smem, int blk,
        const float* __restrict__ wtd, const float* __restrict__ Wf,
        const float* __restrict__ Wfb, float* __restrict__ ybp) {
    const int tid = threadIdx.x;
    const int arow = tid >> 2, akc = (tid & 3) * 8;
    const int bkk  = tid >> 3, bnc = (tid & 7) * 8;
    const int part = blk / 48, tile = blk % 48;
    const int m0 = (tile / 12) * 64, n0 = (tile % 12) * 64, kbeg = part * 192;
    const float* ap = &wtd[(size_t)(m0 + arow) * TWOH + kbeg + akc];
    const float* bq = &Wf[(size_t)(kbeg + bkk) * HD + n0 + bnc];
    auto al = [&](int t, float4& v0, float4& v1_) {
        const float* p = ap + t * 32;
        v0 = *(const float4*)p; v1_ = *(const float4*)(p + 4);
    };
    auto bl = [&](int t, float4& v0, float4& v1_) {
        const float* p = bq + (size_t)t * 32 * HD;
        v0 = *(const float4*)p; v1_ = *(const float4*)(p + 4);
    };
    gemm_core<false>(smem, al, bl, part == 0 ? Wfb : nullptr,
                     ybp + (size_t)part * BD * HD, HD, m0, n0, 6);
}

__device__ __forceinline__ float block_sum256(float v, float* red, int w, int lane) {
    #pragma unroll
    for (int off = 32; off > 0; off >>= 1) v += __shfl_xor(v, off);
    __syncthreads();
    if (lane == 0) red[w] = v;
    __syncthreads();
    return red[0] + red[1] + red[2] + red[3];
}

__device__ void ph_fuse(float* red, int b,
        const float* __restrict__ icpp, const float* __restrict__ Pp,
        const float* __restrict__ ivp, const float* __restrict__ tf,
        const float* __restrict__ in_g, const float* __restrict__ in_b,
        const float* __restrict__ tn_g, const float* __restrict__ tn_b,
        const float* __restrict__ Wg, const float* __restrict__ bg,
        float* __restrict__ wtd) {
    const int tid = threadIdx.x;
    const int w = tid >> 6, lane = tid & 63;
    float icv[3], tcv[3];
    #pragma unroll
    for (int j = 0; j < 3; ++j) {
        int c = j * 256 + tid;
        float pv = 0.f, ic = 0.f, iv = 0.f;
        #pragma unroll
        for (int q = 0; q < 4; ++q) {
            pv += Pp[(size_t)q * BD * HD + b * HD + c];
            ic += icpp[(size_t)q * BD * HD + b * HD + c];
            iv += ivp[(size_t)q * BD * HD + b * HD + c];
        }
        icv[j] = ic + pv;
        tcv[j] = iv + tf[(size_t)b * SD * HD + c];
    }
    float s_i  = block_sum256(icv[0] + icv[1] + icv[2], red, w, lane);
    float ss_i = block_sum256(icv[0]*icv[0] + icv[1]*icv[1] + icv[2]*icv[2], red, w, lane);
    float s_t  = block_sum256(tcv[0] + tcv[1] + tcv[2], red, w, lane);
    float ss_t = block_sum256(tcv[0]*tcv[0] + tcv[1]*tcv[1] + tcv[2]*tcv[2], red, w, lane);
    const float invh = 1.f / HD;
    float mu_i = s_i * invh, var_i = ss_i * invh - mu_i * mu_i;
    float mu_t = s_t * invh, var_t = ss_t * invh - mu_t * mu_t;
    float rs_i = rsqrtf(var_i + EPSV), rs_t = rsqrtf(var_t + EPSV);
    float icn[3], tcn[3];
    #pragma unroll
    for (int j = 0; j < 3; ++j) {
        int c = j * 256 + tid;
        icn[j] = (icv[j] - mu_i) * rs_i * in_g[c] + in_b[c];
        tcn[j] = (tcv[j] - mu_t) * rs_t * tn_g[c] + tn_b[c];
    }
    float z0p = 0.f, z1p = 0.f;
    #pragma unroll
    for (int j = 0; j < 3; ++j) {
        int c = j * 256 + tid;
        z0p += tcn[j] * Wg[c * 2 + 0] + icn[j] * Wg[(HD + c) * 2 + 0];
        z1p += tcn[j] * Wg[c * 2 + 1] + icn[j] * Wg[(HD + c) * 2 + 1];
    }
    float z0 = block_sum256(z0p, red, w, lane) + bg[0];
    float z1 = block_sum256(z1p, red, w, lane) + bg[1];
    float mx = fmaxf(z0, z1);
    float e0 = __expf(z0 - mx), e1 = __expf(z1 - mx);
    float inv = 1.f / (e0 + e1);
    float g0 = e0 * inv, g1 = e1 * inv;
    #pragma unroll
    for (int j = 0; j < 3; ++j) {
        int c = j * 256 + tid;
        wtd[(size_t)b * TWOH + c]      = tcn[j] * g0;
        wtd[(size_t)b * TWOH + HD + c] = icn[j] * g1;
    }
}

__device__ void ph_final(float* red, int b,
        const float* __restrict__ ybp, const float* __restrict__ fn_g,
        const float* __restrict__ fn_b, float* __restrict__ out) {
    const int tid = threadIdx.x;
    const int w = tid >> 6, lane = tid & 63;
    float v[3];
    #pragma unroll
    for (int j = 0; j < 3; ++j) {
        int c = j * 256 + tid;
        float x = 0.f;
        #pragma unroll
        for (int q = 0; q < 8; ++q) x += ybp[(size_t)q * BD * HD + b * HD + c];
        v[j] = x;
    }
    float s  = block_sum256(v[0] + v[1] + v[2], red, w, lane);
    float ss = block_sum256(v[0]*v[0] + v[1]*v[1] + v[2]*v[2], red, w, lane);
    const float invh = 1.f / HD;
    float mu = s * invh, var = ss * invh - mu * mu;
    float rs = rsqrtf(var + EPSV);
    #pragma unroll
    for (int j = 0; j < 3; ++j) {
        int c = j * 256 + tid;
        float x = (v[j] - mu) * rs * fn_g[c] + fn_b[c];
        float g = 0.5f * x * (1.f + erff(x * 0.7071067811865476f));
        out[b * HD + c] = g;
    }
}

// ---------------------------------------------------------------------------
// Persistent mega-kernel: 7 phases, 6 atomic grid barriers (no coop API).
// 512 blocks x 256 threads; LDS ~21.5KB; launch_bounds(256,2) -> 2 blocks/CU
// guaranteed capacity = 512 = grid, all co-resident.
// ---------------------------------------------------------------------------
struct MegaParams {
    const float *tf, *imgf, *Wp, *bp, *Wiv, *biv, *Wiq, *biq, *Wtk, *Wtv, *btv,
                *tn_g, *tn_b, *in_g, *in_b, *Wf, *Wfb, *fn_g, *fn_b, *Wg, *bg;
    float *Pp, *Wqkp, *v1, *qtp, *ivp, *icpp, *ybp, *wtd, *pacc, *ml, *out;
    unsigned* cnt;
};

__global__ __launch_bounds__(256, 2) void mega(MegaParams P) {
    __shared__ __align__(16) char arena[sizeof(GemmSmem)];   // 20.5KB
    __shared__ float wgt[64][SPLIT];
    __shared__ float redm[4];
    GemmSmem& smem = *reinterpret_cast<GemmSmem*>(arena);
    float (*sacc)[HD] = reinterpret_cast<float(*)[HD]>(arena);   // 12288B
    float* sm_ = reinterpret_cast<float*>(arena + 12288);
    float* sl_ = reinterpret_cast<float*>(arena + 12304);
    const int blk = blockIdx.x;
    unsigned* cnt = P.cnt;

    for (int vb = blk; vb < 780; vb += (int)GRIDN)
        ph_stage1(smem, vb, P.imgf, P.Wp, P.bp, P.Wiq, P.Wtk, P.biq,
                  P.Pp, P.Wqkp, P.v1);
    gbar(cnt, 1);
    if (blk < 384) ph_stage2(smem, blk, P.Pp, P.Wqkp, P.v1, P.Wiv, P.biv,
                             P.qtp, P.ivp);
    gbar(cnt, 2);
    for (int it = blk; it < BD * SPLIT; it += (int)GRIDN)
        ph_attn(sacc, sm_, sl_, it, P.tf, P.qtp, P.pacc, P.ml);
    gbar(cnt, 3);
    if (blk < 192) ph_ctxv(smem, wgt, blk, P.pacc, P.ml, P.Wtv, P.btv, P.icpp);
    gbar(cnt, 4);
    if (blk < 256) ph_fuse(redm, blk, P.icpp, P.Pp, P.ivp, P.tf, P.in_g, P.in_b,
                           P.tn_g, P.tn_b, P.Wg, P.bg, P.wtd);
    gbar(cnt, 5);
    if (blk < 384) ph_wf(smem, blk, P.wtd, P.Wf, P.Wfb, P.ybp);
    gbar(cnt, 6);
    if (blk < 256) ph_final(redm, blk, P.ybp, P.fn_g, P.fn_b, P.out);
}

// ---------------------------------------------------------------------------
extern "C" void kernel_launch(void* const* d_in, const int* in_sizes, int n_in,
                              void* d_out, int out_size, void* d_ws, size_t ws_size,
                              hipStream_t stream) {
    const float* tf   = (const float*)d_in[0];
    const float* imgf = (const float*)d_in[1];
    const float* Wp   = (const float*)d_in[2];
    const float* bp   = (const float*)d_in[3];
    // d_in[4..7] (Wtq,btq,Wik,bik): dead — softmax over 1 element == 1 exactly
    const float* Wiv  = (const float*)d_in[8];
    const float* biv  = (const float*)d_in[9];
    const float* Wiq  = (const float*)d_in[10];
    const float* biq  = (const float*)d_in[11];
    const float* Wtk  = (const float*)d_in[12];
    // d_in[13] (btk): per-b constant on scores — softmax-invariant, dropped
    const float* Wtv  = (const float*)d_in[14];
    const float* btv  = (const float*)d_in[15];
    const float* tn_g = (const float*)d_in[16];
    const float* tn_b = (const float*)d_in[17];
    const float* in_g = (const float*)d_in[18];
    const float* in_b = (const float*)d_in[19];
    const float* Wf   = (const float*)d_in[20];
    const float* bff  = (const float*)d_in[21];
    const float* fn_g = (const float*)d_in[22];
    const float* fn_b = (const float*)d_in[23];
    const float* Wg   = (const float*)d_in[24];
    const float* bg   = (const float*)d_in[25];

    float* ws    = (float*)d_ws;
    float* Pp    = ws;                      // 4 * B*H
    float* Wqkp  = Pp    + 4 * BD * HD;     // 4 * H*H
    float* v1    = Wqkp  + 4 * HD * HD;     // H
    float* qtp   = v1    + HD;              // 4 * B*H
    float* ivp   = qtp   + 4 * BD * HD;     // 4 * B*H
    float* icpp  = ivp   + 4 * BD * HD;     // 4 * B*H
    float* ybp   = icpp  + 4 * BD * HD;     // 8 * B*H
    float* wtd   = ybp   + 8 * BD * HD;     // B*2H
    float* pacc  = wtd   + BD * TWOH;       // B*SPLIT*H
    float* ml    = pacc  + (size_t)BD * SPLIT * HD;  // B*SPLIT*2
    unsigned* cnt = (unsigned*)(ml + (size_t)BD * SPLIT * 2);

    MegaParams prm;
    prm.tf = tf; prm.imgf = imgf; prm.Wp = Wp; prm.bp = bp;
    prm.Wiv = Wiv; prm.biv = biv; prm.Wiq = Wiq; prm.biq = biq;
    prm.Wtk = Wtk; prm.Wtv = Wtv; prm.btv = btv;
    prm.tn_g = tn_g; prm.tn_b = tn_b; prm.in_g = in_g; prm.in_b = in_b;
    prm.Wf = Wf; prm.Wfb = bff; prm.fn_g = fn_g; prm.fn_b = fn_b;
    prm.Wg = Wg; prm.bg = bg;
    prm.Pp = Pp; prm.Wqkp = Wqkp; prm.v1 = v1; prm.qtp = qtp; prm.ivp = ivp;
    prm.icpp = icpp; prm.ybp = ybp; prm.wtd = wtd; prm.pacc = pacc; prm.ml = ml;
    prm.out = (float*)d_out;
    prm.cnt = cnt;

    // Barrier counter MUST be 0 at kernel start (round-indexed targets).
    // Async memset is graph-capturable and replays before every launch.
    hipMemsetAsync(cnt, 0, sizeof(unsigned), stream);
    mega<<<dim3((int)GRIDN), dim3(256), 0, stream>>>(prm);
}